// Round 17
// baseline (280.480 us; speedup 1.0000x reference)
//
#include <hip/hip_runtime.h>
#include <math.h>
#include <stdint.h>

#define NG 8
#define GS 2048
#define DM 512
#define NE 64
#define CAP 32
#define NROWS (NG * GS)                       // 16384 total rows (g,s)
#define COMBINE_ELEMS (33554432ull)           // 8*2048*64*32

#define GATE_BLOCKS 512                       // 32 rows per block, 4 waves
#define XST 516                               // staged x row stride (words)
#define TBS 21                                // transpose buffer stride (odd)

// Sacrificial measurement: inflate ONLY gate so its rocprof row surfaces
// (R12 lesson: top-5 fills with the single slowest kernel's replicas, so
// one variable per round). G = row/8, cross-check G = (total-120)/7.
// REMOVE NEXT ROUND.
#define GATE_REP 8

typedef float f32x4 __attribute__((ext_vector_type(4)));
typedef double f64x2 __attribute__((ext_vector_type(2)));
typedef double f64x4 __attribute__((ext_vector_type(4)));
typedef unsigned long long u64;

// ---------------------------------------------------------------------------
// JAX Threefry-2x32 (partitionable path).  [verified: rounds 1,3-5,7-16]
// ---------------------------------------------------------------------------
__device__ __forceinline__ void threefry2x32(uint32_t k0, uint32_t k1,
                                             uint32_t x0, uint32_t x1,
                                             uint32_t& o0, uint32_t& o1) {
  uint32_t ks[3] = {k0, k1, k0 ^ k1 ^ 0x1BD11BDAu};
  x0 += ks[0];
  x1 += ks[1];
  const uint32_t rot[2][4] = {{13u, 15u, 26u, 6u}, {17u, 29u, 16u, 24u}};
#pragma unroll
  for (int i = 0; i < 5; ++i) {
#pragma unroll
    for (int j = 0; j < 4; ++j) {
      uint32_t r = rot[i & 1][j];
      x0 += x1;
      x1 = (x1 << r) | (x1 >> (32u - r));
      x1 ^= x0;
    }
    x0 += ks[(i + 1) % 3];
    x1 += ks[(i + 2) % 3] + (uint32_t)(i + 1);
  }
  o0 = x0;
  o1 = x1;
}

// XLA ErfInv (f32), Giles polynomial — constants bit-match xla math.cc.
__device__ __forceinline__ float erfinv_xla(float x) {
  float w = -log1pf(-x * x);
  float p;
  if (w < 5.0f) {
    w = w - 2.5f;
    p = 2.81022636e-08f;
    p = __fmaf_rn(p, w, 3.43273939e-07f);
    p = __fmaf_rn(p, w, -3.5233877e-06f);
    p = __fmaf_rn(p, w, -4.39150654e-06f);
    p = __fmaf_rn(p, w, 0.00021858087f);
    p = __fmaf_rn(p, w, -0.00125372503f);
    p = __fmaf_rn(p, w, -0.00417768164f);
    p = __fmaf_rn(p, w, 0.246640727f);
    p = __fmaf_rn(p, w, 1.50140941f);
  } else {
    w = sqrtf(w) - 3.0f;
    p = -0.000200214257f;
    p = __fmaf_rn(p, w, 0.000100950558f);
    p = __fmaf_rn(p, w, 0.00134934322f);
    p = __fmaf_rn(p, w, -0.00367342844f);
    p = __fmaf_rn(p, w, 0.00573950773f);
    p = __fmaf_rn(p, w, -0.0076224613f);
    p = __fmaf_rn(p, w, 0.00943887047f);
    p = __fmaf_rn(p, w, 1.00167406f);
    p = __fmaf_rn(p, w, 2.83297682f);
  }
  return p * x;
}

__device__ __forceinline__ float jax_normal(uint32_t idx) {
  uint32_t o0, o1;
  threefry2x32(0u, 42u, 0u, idx, o0, o1);
  uint32_t bits = o0 ^ o1;
  float f = __uint_as_float((bits >> 9) | 0x3f800000u) - 1.0f;  // [0,1)
  const float lo = __uint_as_float(0xBF7FFFFFu);                // -0.99999994
  float v = fmaxf(lo, f * 2.0f + lo);
  return __uint_as_float(0x3FB504F3u) * erfinv_xla(v);  // sqrt(2)_f32 * erfinv
}

// ---------------------------------------------------------------------------
// Kernel P: reformat W -> f64, layout Wd[row=kk*4+k4][i15][t].  [r14]
// ---------------------------------------------------------------------------
__global__ __launch_bounds__(256) void wprep_kernel(
    const float* __restrict__ Wt, double* __restrict__ Wd) {
  const int i = blockIdx.x * 256 + threadIdx.x;   // 0..32767
  const int t = i & 3, i15 = (i >> 2) & 15, row = i >> 6;
  Wd[i] = (double)Wt[row * NE + t * 16 + i15];
}

// ---------------------------------------------------------------------------
// Kernel 1: gate — R16 K-split structure, body repeated GATE_REP times
// (idempotent; early-return converted to conditional epilogue so all waves
// stay for the rep-loop barriers).
// ---------------------------------------------------------------------------
__global__ __launch_bounds__(256) void gate_kernel(
    const float* __restrict__ x,    // (NROWS, 512)
    const double* __restrict__ Wd,  // (512, 16, 4) prepped
    float* __restrict__ gatesT) {   // (NG*NE, GS)
  __shared__ float xs[32 * XST];    // 66048 B -> 2 blocks/CU
  const int gid = blockIdx.x;         // 0..511
  const int tid = threadIdx.x;
  const int l = tid & 63;             // lane
  const int w4 = tid >> 6;            // wave 0..3
  const int wr = w4 & 1;              // row-tile
  const int kh = w4 >> 1;             // k-half
  const int row0b = gid * 32;
  const int row0 = row0b + wr * 16;

  const int i15 = l & 15;
  const int k4 = l >> 4;

  // --- runtime probe: which x-row does acc[*][r] hold?  [verified r7-r16]
  f64x4 dr = {0., 0., 0., 0.};
  dr = __builtin_amdgcn_mfma_f64_16x16x4f64((double)i15, 0.25, dr, 0, 0, 0);
  int perm[4];
#pragma unroll
  for (int r = 0; r < 4; ++r) perm[r] = ((int)(dr[r] + 0.5)) & 15;

  for (int rep = 0; rep < GATE_REP; ++rep) {
    asm volatile("" ::: "memory");
    __syncthreads();   // protect xs reuse across reps (tb overlap)

    // stage the whole 32x512 tile
#pragma unroll 8
    for (int i = tid; i < 4096; i += 256) {
      const int r = i >> 7, c = (i & 127) << 2;
      *(f32x4*)&xs[r * XST + c] =
          *(const f32x4*)&x[(size_t)(row0b + r) * DM + c];
    }
    __syncthreads();

    // K-loop over this wave's half: kk in [64*kh, 64*kh+64).
    f64x4 acc[4] = {{0., 0., 0., 0.}, {0., 0., 0., 0.},
                    {0., 0., 0., 0.}, {0., 0., 0., 0.}};
    const float* xrow = &xs[(wr * 16 + i15) * XST + k4];
    const double* wl = Wd + k4 * 64 + i15 * 4;
    const int kk0 = kh * 64;
    f64x2 b01 = *(const f64x2*)(wl + (size_t)kk0 * 256 + 0);
    f64x2 b23 = *(const f64x2*)(wl + (size_t)kk0 * 256 + 2);
#pragma unroll 4
    for (int kk = kk0; kk < kk0 + 64; ++kk) {
      const int nk = (kk + 1) & 127;
      const f64x2 nb01 = *(const f64x2*)(wl + (size_t)nk * 256 + 0);
      const f64x2 nb23 = *(const f64x2*)(wl + (size_t)nk * 256 + 2);
      const double a = (double)xrow[kk * 4];
      acc[0] = __builtin_amdgcn_mfma_f64_16x16x4f64(a, b01[0], acc[0], 0, 0, 0);
      acc[1] = __builtin_amdgcn_mfma_f64_16x16x4f64(a, b01[1], acc[1], 0, 0, 0);
      acc[2] = __builtin_amdgcn_mfma_f64_16x16x4f64(a, b23[0], acc[2], 0, 0, 0);
      acc[3] = __builtin_amdgcn_mfma_f64_16x16x4f64(a, b23[1], acc[3], 0, 0, 0);
      b01 = nb01;
      b23 = nb23;
    }
    __syncthreads();   // x-tile fully read -> reusable

    // kh=1 waves dump partials into dead x LDS (floats [4096,8192)).
    double* pd = (double*)&xs[4096];
    if (kh == 1) {
      double* dst = pd + ((size_t)(wr * 64 + l)) * 16;
#pragma unroll
      for (int t = 0; t < 4; ++t)
#pragma unroll
        for (int r = 0; r < 4; ++r) dst[t * 4 + r] = acc[t][r];
    }
    __syncthreads();

    if (kh == 0) {
      const double* src = pd + ((size_t)(wr * 64 + l)) * 16;
#pragma unroll
      for (int t = 0; t < 4; ++t)
#pragma unroll
        for (int r = 0; r < 4; ++r) acc[t][r] += src[t * 4 + r];

      // noise + fp64 softmax
      float gatef[4][4];  // [t][r]
#pragma unroll
      for (int r = 0; r < 4; ++r) {
        const int row = row0 + perm[r];
        double v[4];
        double m = -1.0e300;
#pragma unroll
        for (int t = 0; t < 4; ++t) {
          const float logit = (float)acc[t][r];
          const float noised =
              logit + 0.015625f * jax_normal((uint32_t)(row * NE + 16 * t + i15));
          v[t] = (double)noised;
          m = fmax(m, v[t]);
        }
#pragma unroll
        for (int off = 1; off < 16; off <<= 1)
          m = fmax(m, __shfl_xor(m, off, 64));
        double s = 0.0;
#pragma unroll
        for (int t = 0; t < 4; ++t) {
          v[t] = exp(v[t] - m);
          s += v[t];
        }
#pragma unroll
        for (int off = 1; off < 16; off <<= 1) s += __shfl_xor(s, off, 64);
#pragma unroll
        for (int t = 0; t < 4; ++t) gatef[t][r] = (float)(v[t] / s);
      }

      // per-wave LDS transpose into private region (floats [0,2688)).
      float* tb = xs + wr * (NE * TBS);
#pragma unroll
      for (int t = 0; t < 4; ++t)
#pragma unroll
        for (int r = 0; r < 4; ++r)
          tb[(16 * t + i15) * TBS + perm[r]] = gatef[t][r];

      const int g = row0 >> 11;
      const int s0 = row0 & (GS - 1);
      float* drow = gatesT + ((size_t)(g * NE + l)) * GS + s0;
#pragma unroll
      for (int c = 0; c < 4; ++c) {
        f32x4 o;
#pragma unroll
        for (int i = 0; i < 4; ++i) o[i] = tb[l * TBS + 4 * c + i];
        *(f32x4*)&drow[4 * c] = o;
      }
    }
  }
}

// ---------------------------------------------------------------------------
// Kernel 2: topsel — bitonic merge-prune top-32 per (g,e), keys-only.
// [verified r13-r16]
// ---------------------------------------------------------------------------
__global__ __launch_bounds__(64) void topsel_kernel(
    const float* __restrict__ gatesT,  // (NG*NE, GS)
    u64* __restrict__ topsel) {        // (NG*NE, CAP)
  const int ge = blockIdx.x;  // == g*64 + e
  const int lane = threadIdx.x;

  const float* base = gatesT + (size_t)ge * GS;
  u64 K[32];
#pragma unroll
  for (int k = 0; k < 8; ++k) {
    const f32x4 t = *(const f32x4*)(base + k * 256 + lane * 4);
#pragma unroll
    for (int i = 0; i < 4; ++i) {
      const int s = k * 256 + lane * 4 + i;
      K[k * 4 + i] = ((u64)__float_as_uint(t[i]) << 32) | (u64)(2047 - s);
    }
  }

  // per-lane bitonic sort of 32 keys, ascending
#pragma unroll
  for (int k = 2; k <= 32; k <<= 1) {
#pragma unroll
    for (int d = k >> 1; d > 0; d >>= 1) {
#pragma unroll
      for (int j = 0; j < 32; ++j) {
        const int ixj = j ^ d;
        if (ixj > j) {
          const bool asc = ((j & k) == 0);
          const u64 a = K[j], b = K[ixj];
          const bool sw = asc ? (a > b) : (a < b);
          K[j] = sw ? b : a;
          K[ixj] = sw ? a : b;
        }
      }
    }
  }

  // 6 butterfly merge-prune levels
#pragma unroll
  for (int m = 1; m < 64; m <<= 1) {
    u64 tmp[32];
#pragma unroll
    for (int j = 0; j < 32; ++j) tmp[j] = __shfl_xor(K[31 - j], m, 64);
#pragma unroll
    for (int j = 0; j < 32; ++j) K[j] = (K[j] > tmp[j]) ? K[j] : tmp[j];
#pragma unroll
    for (int d = 16; d > 0; d >>= 1) {
#pragma unroll
      for (int j = 0; j < 32; ++j) {
        if ((j & d) == 0) {
          const u64 a = K[j], b = K[j | d];
          const bool sw = (a > b);
          K[j] = sw ? b : a;
          K[j | d] = sw ? a : b;
        }
      }
    }
  }

#pragma unroll
  for (int c = 0; c < CAP; ++c) {
    if (lane == c) topsel[(size_t)ge * CAP + c] = K[31 - c];
  }
}

// ---------------------------------------------------------------------------
// Kernel 3: writer — dense single-pass output (zeros + values).  [r15]
// ---------------------------------------------------------------------------
__global__ __launch_bounds__(256) void writer_kernel(
    const u64* __restrict__ topsel,   // (NG*NE, CAP)
    float* __restrict__ out) {        // combine ++ dispatch
  __shared__ int sel_s[CAP];
  __shared__ float sel_v[CAP];
  __shared__ unsigned char c_of_s[GS];
  const int b = blockIdx.x;
  const int ge = b >> 2, q = b & 3;
  const int g = ge >> 6, e = ge & 63;
  const int tid = threadIdx.x;
  const int lane = tid & 63, w = tid >> 6;

  ((u64*)c_of_s)[tid] = ~0ull;
  if (tid < CAP) {
    const u64 key = topsel[(size_t)ge * CAP + tid];
    sel_s[tid] = 2047 - (int)(key & 0x7FFull);
    sel_v[tid] = __uint_as_float((uint32_t)(key >> 32));
  }
  __syncthreads();
  if (tid < CAP) c_of_s[sel_s[tid]] = (unsigned char)tid;
  __syncthreads();

  // ---- dispatch (G,E,C,S): rows c = 8q + 2w + {0,1} ----
  float* drow_base = out + COMBINE_ELEMS + (size_t)ge * CAP * GS;
#pragma unroll
  for (int rr = 0; rr < 2; ++rr) {
    const int c = 8 * q + 2 * w + rr;
    const int sc = sel_s[c];
    float* rowp = drow_base + (size_t)c * GS;
#pragma unroll
    for (int j = 0; j < 8; ++j) {
      const int pos = j * 256 + lane * 4;
      f32x4 v;
      v[0] = (sc == pos + 0) ? 1.0f : 0.0f;
      v[1] = (sc == pos + 1) ? 1.0f : 0.0f;
      v[2] = (sc == pos + 2) ? 1.0f : 0.0f;
      v[3] = (sc == pos + 3) ? 1.0f : 0.0f;
      *(f32x4*)&rowp[pos] = v;
    }
  }

  // ---- combine (G,S,E,C) ----
  const int pos = (lane & 7) * 4;
#pragma unroll
  for (int it = 0; it < 16; ++it) {
    const int s = 512 * q + 128 * w + 8 * it + (lane >> 3);
    const int c = c_of_s[s];
    const float val = (c != 255) ? sel_v[c & 31] : 0.0f;
    const int d = c - pos;
    f32x4 v;
    v[0] = (d == 0) ? val : 0.0f;
    v[1] = (d == 1) ? val : 0.0f;
    v[2] = (d == 2) ? val : 0.0f;
    v[3] = (d == 3) ? val : 0.0f;
    *(f32x4*)&out[(((size_t)(g * GS + s)) * NE + e) * CAP + pos] = v;
  }
}

extern "C" void kernel_launch(void* const* d_in, const int* in_sizes, int n_in,
                              void* d_out, int out_size, void* d_ws,
                              size_t ws_size, hipStream_t stream) {
  (void)in_sizes; (void)n_in; (void)ws_size; (void)out_size;
  const float* x = (const float*)d_in[0];   // (8,2048,512) f32
  const float* Wt = (const float*)d_in[1];  // (512,64) f32
  float* out = (float*)d_out;
  float* gatesT = (float*)d_ws;                                    // 4 MB
  double* Wd = (double*)((char*)d_ws + ((size_t)NROWS * NE * 4));  // 256 KB
  u64* topsel = (u64*)((char*)Wd + (size_t)DM * NE * 8);           // 128 KB

  wprep_kernel<<<128, 256, 0, stream>>>(Wt, Wd);
  gate_kernel<<<GATE_BLOCKS, 256, 0, stream>>>(x, Wd, gatesT);
  topsel_kernel<<<NG * NE, 64, 0, stream>>>(gatesT, topsel);
  writer_kernel<<<NG * NE * 4, 256, 0, stream>>>(topsel, out);
}

// Round 18
// 115.462 us; speedup vs baseline: 2.4292x; 2.4292x over previous
//
#include <hip/hip_runtime.h>
#include <math.h>
#include <stdint.h>

#define NG 8
#define GS 2048
#define DM 512
#define NE 64
#define CAP 32
#define NROWS (NG * GS)                       // 16384 total rows (g,s)
#define COMBINE_ELEMS (33554432ull)           // 8*2048*64*32

#define GATE_BLOCKS 512                       // 32 rows per block, 4 waves
#define XST 516                               // staged x row stride (words)
#define TBS 21                                // transpose buffer stride (odd)

typedef float f32x4 __attribute__((ext_vector_type(4)));
typedef double f64x2 __attribute__((ext_vector_type(2)));
typedef double f64x4 __attribute__((ext_vector_type(4)));
typedef unsigned long long u64;

// ---------------------------------------------------------------------------
// JAX Threefry-2x32 (partitionable path).  [verified: rounds 1,3-5,7-17]
// ---------------------------------------------------------------------------
__device__ __forceinline__ void threefry2x32(uint32_t k0, uint32_t k1,
                                             uint32_t x0, uint32_t x1,
                                             uint32_t& o0, uint32_t& o1) {
  uint32_t ks[3] = {k0, k1, k0 ^ k1 ^ 0x1BD11BDAu};
  x0 += ks[0];
  x1 += ks[1];
  const uint32_t rot[2][4] = {{13u, 15u, 26u, 6u}, {17u, 29u, 16u, 24u}};
#pragma unroll
  for (int i = 0; i < 5; ++i) {
#pragma unroll
    for (int j = 0; j < 4; ++j) {
      uint32_t r = rot[i & 1][j];
      x0 += x1;
      x1 = (x1 << r) | (x1 >> (32u - r));
      x1 ^= x0;
    }
    x0 += ks[(i + 1) % 3];
    x1 += ks[(i + 2) % 3] + (uint32_t)(i + 1);
  }
  o0 = x0;
  o1 = x1;
}

// XLA ErfInv (f32), Giles polynomial — constants bit-match xla math.cc.
__device__ __forceinline__ float erfinv_xla(float x) {
  float w = -log1pf(-x * x);
  float p;
  if (w < 5.0f) {
    w = w - 2.5f;
    p = 2.81022636e-08f;
    p = __fmaf_rn(p, w, 3.43273939e-07f);
    p = __fmaf_rn(p, w, -3.5233877e-06f);
    p = __fmaf_rn(p, w, -4.39150654e-06f);
    p = __fmaf_rn(p, w, 0.00021858087f);
    p = __fmaf_rn(p, w, -0.00125372503f);
    p = __fmaf_rn(p, w, -0.00417768164f);
    p = __fmaf_rn(p, w, 0.246640727f);
    p = __fmaf_rn(p, w, 1.50140941f);
  } else {
    w = sqrtf(w) - 3.0f;
    p = -0.000200214257f;
    p = __fmaf_rn(p, w, 0.000100950558f);
    p = __fmaf_rn(p, w, 0.00134934322f);
    p = __fmaf_rn(p, w, -0.00367342844f);
    p = __fmaf_rn(p, w, 0.00573950773f);
    p = __fmaf_rn(p, w, -0.0076224613f);
    p = __fmaf_rn(p, w, 0.00943887047f);
    p = __fmaf_rn(p, w, 1.00167406f);
    p = __fmaf_rn(p, w, 2.83297682f);
  }
  return p * x;
}

__device__ __forceinline__ float jax_normal(uint32_t idx) {
  uint32_t o0, o1;
  threefry2x32(0u, 42u, 0u, idx, o0, o1);
  uint32_t bits = o0 ^ o1;
  float f = __uint_as_float((bits >> 9) | 0x3f800000u) - 1.0f;  // [0,1)
  const float lo = __uint_as_float(0xBF7FFFFFu);                // -0.99999994
  float v = fmaxf(lo, f * 2.0f + lo);
  return __uint_as_float(0x3FB504F3u) * erfinv_xla(v);  // sqrt(2)_f32 * erfinv
}

// ---------------------------------------------------------------------------
// Kernel P: reformat W -> f64, layout Wd[row=kk*4+k4][i15][t].  [r14]
// ---------------------------------------------------------------------------
__global__ __launch_bounds__(256) void wprep_kernel(
    const float* __restrict__ Wt, double* __restrict__ Wd) {
  const int i = blockIdx.x * 256 + threadIdx.x;   // 0..32767
  const int t = i & 3, i15 = (i >> 2) & 15, row = i >> 6;
  Wd[i] = (double)Wt[row * NE + t * 16 + i15];
}

// ---------------------------------------------------------------------------
// Kernel 1: gate — R16 K-split (steady-state ~23 us, MfmaUtil 49%,
// measured r17). Rep loop removed.
// ---------------------------------------------------------------------------
__global__ __launch_bounds__(256) void gate_kernel(
    const float* __restrict__ x,    // (NROWS, 512)
    const double* __restrict__ Wd,  // (512, 16, 4) prepped
    float* __restrict__ gatesT) {   // (NG*NE, GS)
  __shared__ float xs[32 * XST];    // 66048 B -> 2 blocks/CU
  const int gid = blockIdx.x;         // 0..511
  const int tid = threadIdx.x;
  const int l = tid & 63;             // lane
  const int w4 = tid >> 6;            // wave 0..3
  const int wr = w4 & 1;              // row-tile
  const int kh = w4 >> 1;             // k-half
  const int row0b = gid * 32;
  const int row0 = row0b + wr * 16;

  const int i15 = l & 15;
  const int k4 = l >> 4;

  // --- runtime probe: which x-row does acc[*][r] hold?  [verified r7-r17]
  f64x4 dr = {0., 0., 0., 0.};
  dr = __builtin_amdgcn_mfma_f64_16x16x4f64((double)i15, 0.25, dr, 0, 0, 0);
  int perm[4];
#pragma unroll
  for (int r = 0; r < 4; ++r) perm[r] = ((int)(dr[r] + 0.5)) & 15;

  // stage the whole 32x512 tile
#pragma unroll 8
  for (int i = tid; i < 4096; i += 256) {
    const int r = i >> 7, c = (i & 127) << 2;
    *(f32x4*)&xs[r * XST + c] =
        *(const f32x4*)&x[(size_t)(row0b + r) * DM + c];
  }
  __syncthreads();

  // K-loop over this wave's half: kk in [64*kh, 64*kh+64).
  f64x4 acc[4] = {{0., 0., 0., 0.}, {0., 0., 0., 0.},
                  {0., 0., 0., 0.}, {0., 0., 0., 0.}};
  const float* xrow = &xs[(wr * 16 + i15) * XST + k4];
  const double* wl = Wd + k4 * 64 + i15 * 4;
  const int kk0 = kh * 64;
  f64x2 b01 = *(const f64x2*)(wl + (size_t)kk0 * 256 + 0);
  f64x2 b23 = *(const f64x2*)(wl + (size_t)kk0 * 256 + 2);
#pragma unroll 4
  for (int kk = kk0; kk < kk0 + 64; ++kk) {
    const int nk = (kk + 1) & 127;
    const f64x2 nb01 = *(const f64x2*)(wl + (size_t)nk * 256 + 0);
    const f64x2 nb23 = *(const f64x2*)(wl + (size_t)nk * 256 + 2);
    const double a = (double)xrow[kk * 4];
    acc[0] = __builtin_amdgcn_mfma_f64_16x16x4f64(a, b01[0], acc[0], 0, 0, 0);
    acc[1] = __builtin_amdgcn_mfma_f64_16x16x4f64(a, b01[1], acc[1], 0, 0, 0);
    acc[2] = __builtin_amdgcn_mfma_f64_16x16x4f64(a, b23[0], acc[2], 0, 0, 0);
    acc[3] = __builtin_amdgcn_mfma_f64_16x16x4f64(a, b23[1], acc[3], 0, 0, 0);
    b01 = nb01;
    b23 = nb23;
  }
  __syncthreads();   // x-tile fully read -> reusable

  // kh=1 waves dump partials into dead x LDS (floats [4096,8192)).
  double* pd = (double*)&xs[4096];
  if (kh == 1) {
    double* dst = pd + ((size_t)(wr * 64 + l)) * 16;
#pragma unroll
    for (int t = 0; t < 4; ++t)
#pragma unroll
      for (int r = 0; r < 4; ++r) dst[t * 4 + r] = acc[t][r];
  }
  __syncthreads();
  if (kh == 1) return;

  {
    const double* src = pd + ((size_t)(wr * 64 + l)) * 16;
#pragma unroll
    for (int t = 0; t < 4; ++t)
#pragma unroll
      for (int r = 0; r < 4; ++r) acc[t][r] += src[t * 4 + r];
  }

  // noise + fp64 softmax. acc[t][r] = logits[row0+perm[r]][e=16t+i15].
  float gatef[4][4];  // [t][r]
#pragma unroll
  for (int r = 0; r < 4; ++r) {
    const int row = row0 + perm[r];
    double v[4];
    double m = -1.0e300;
#pragma unroll
    for (int t = 0; t < 4; ++t) {
      const float logit = (float)acc[t][r];
      const float noised =
          logit + 0.015625f * jax_normal((uint32_t)(row * NE + 16 * t + i15));
      v[t] = (double)noised;
      m = fmax(m, v[t]);
    }
#pragma unroll
    for (int off = 1; off < 16; off <<= 1) m = fmax(m, __shfl_xor(m, off, 64));
    double s = 0.0;
#pragma unroll
    for (int t = 0; t < 4; ++t) {
      v[t] = exp(v[t] - m);
      s += v[t];
    }
#pragma unroll
    for (int off = 1; off < 16; off <<= 1) s += __shfl_xor(s, off, 64);
#pragma unroll
    for (int t = 0; t < 4; ++t) gatef[t][r] = (float)(v[t] / s);
  }

  // per-wave LDS transpose into private region (floats [0,2688), dead x).
  float* tb = xs + wr * (NE * TBS);
#pragma unroll
  for (int t = 0; t < 4; ++t)
#pragma unroll
    for (int r = 0; r < 4; ++r)
      tb[(16 * t + i15) * TBS + perm[r]] = gatef[t][r];

  const int g = row0 >> 11;
  const int s0 = row0 & (GS - 1);
  float* drow = gatesT + ((size_t)(g * NE + l)) * GS + s0;
#pragma unroll
  for (int c = 0; c < 4; ++c) {
    f32x4 o;
#pragma unroll
    for (int i = 0; i < 4; ++i) o[i] = tb[l * TBS + 4 * c + i];
    *(f32x4*)&drow[4 * c] = o;
  }
}

// ---------------------------------------------------------------------------
// Kernel 2: topwrite — ROUND-18 FUSION of topsel+writer. One block per
// (g,e), 4 waves. Wave 0 runs the verified bitonic top-32 [r13-r17]; LDS
// handoff; all 4 waves densely write this ge's 512 KB output slice (zeros +
// values, coalesced). Kills one launch, the topsel->writer dependency
// bubble, and the 128 KB scratch round-trip; resident blocks pipeline one
// block's topsel VALU under another's HBM store stream.
// ---------------------------------------------------------------------------
__global__ __launch_bounds__(256) void topwrite_kernel(
    const float* __restrict__ gatesT,  // (NG*NE, GS)
    float* __restrict__ out) {         // combine ++ dispatch
  __shared__ u64 keys[CAP];
  __shared__ int sel_s[CAP];
  __shared__ float sel_v[CAP];
  __shared__ unsigned char c_of_s[GS];
  const int ge = blockIdx.x;  // == g*64 + e
  const int g = ge >> 6, e = ge & 63;
  const int tid = threadIdx.x;
  const int lane = tid & 63, w = tid >> 6;

  ((u64*)c_of_s)[tid] = ~0ull;  // 256 threads x 8 B = 2048 B

  if (w == 0) {
    // ---- wave 0: bitonic merge-prune top-32 [verified r13-r17] ----
    const float* base = gatesT + (size_t)ge * GS;
    u64 K[32];
#pragma unroll
    for (int k = 0; k < 8; ++k) {
      const f32x4 t = *(const f32x4*)(base + k * 256 + lane * 4);
#pragma unroll
      for (int i = 0; i < 4; ++i) {
        const int s = k * 256 + lane * 4 + i;
        K[k * 4 + i] = ((u64)__float_as_uint(t[i]) << 32) | (u64)(2047 - s);
      }
    }
    // per-lane bitonic sort of 32 keys, ascending
#pragma unroll
    for (int k = 2; k <= 32; k <<= 1) {
#pragma unroll
      for (int d = k >> 1; d > 0; d >>= 1) {
#pragma unroll
        for (int j = 0; j < 32; ++j) {
          const int ixj = j ^ d;
          if (ixj > j) {
            const bool asc = ((j & k) == 0);
            const u64 a = K[j], b = K[ixj];
            const bool sw = asc ? (a > b) : (a < b);
            K[j] = sw ? b : a;
            K[ixj] = sw ? a : b;
          }
        }
      }
    }
    // 6 butterfly merge-prune levels
#pragma unroll
    for (int m = 1; m < 64; m <<= 1) {
      u64 tmp[32];
#pragma unroll
      for (int j = 0; j < 32; ++j) tmp[j] = __shfl_xor(K[31 - j], m, 64);
#pragma unroll
      for (int j = 0; j < 32; ++j) K[j] = (K[j] > tmp[j]) ? K[j] : tmp[j];
#pragma unroll
      for (int d = 16; d > 0; d >>= 1) {
#pragma unroll
        for (int j = 0; j < 32; ++j) {
          if ((j & d) == 0) {
            const u64 a = K[j], b = K[j | d];
            const bool sw = (a > b);
            K[j] = sw ? b : a;
            K[j | d] = sw ? a : b;
          }
        }
      }
    }
#pragma unroll
    for (int c = 0; c < CAP; ++c) {
      if (lane == c) keys[c] = K[31 - c];
    }
  }
  __syncthreads();

  if (tid < CAP) {
    const u64 key = keys[tid];
    sel_s[tid] = 2047 - (int)(key & 0x7FFull);
    sel_v[tid] = __uint_as_float((uint32_t)(key >> 32));
  }
  __syncthreads();
  if (tid < CAP) c_of_s[sel_s[tid]] = (unsigned char)tid;
  __syncthreads();

  // ---- dispatch (G,E,C,S): wave w writes rows c in [8w, 8w+8) ----
  float* drow_base = out + COMBINE_ELEMS + (size_t)ge * CAP * GS;
#pragma unroll
  for (int rr = 0; rr < 8; ++rr) {
    const int c = 8 * w + rr;
    const int sc = sel_s[c];
    float* rowp = drow_base + (size_t)c * GS;
#pragma unroll
    for (int j = 0; j < 8; ++j) {
      const int pos = j * 256 + lane * 4;
      f32x4 v;
      v[0] = (sc == pos + 0) ? 1.0f : 0.0f;
      v[1] = (sc == pos + 1) ? 1.0f : 0.0f;
      v[2] = (sc == pos + 2) ? 1.0f : 0.0f;
      v[3] = (sc == pos + 3) ? 1.0f : 0.0f;
      *(f32x4*)&rowp[pos] = v;
    }
  }

  // ---- combine (G,S,E,C): wave w writes rows s in [512w, 512w+512) ----
  const int pos = (lane & 7) * 4;   // float offset within the 32-float row
  for (int it = 0; it < 64; ++it) {
    const int s = 512 * w + 8 * it + (lane >> 3);
    const int c = c_of_s[s];        // 0..31 or 255
    const float val = (c != 255) ? sel_v[c & 31] : 0.0f;
    const int d = c - pos;
    f32x4 v;
    v[0] = (d == 0) ? val : 0.0f;
    v[1] = (d == 1) ? val : 0.0f;
    v[2] = (d == 2) ? val : 0.0f;
    v[3] = (d == 3) ? val : 0.0f;
    *(f32x4*)&out[(((size_t)(g * GS + s)) * NE + e) * CAP + pos] = v;
  }
}

extern "C" void kernel_launch(void* const* d_in, const int* in_sizes, int n_in,
                              void* d_out, int out_size, void* d_ws,
                              size_t ws_size, hipStream_t stream) {
  (void)in_sizes; (void)n_in; (void)ws_size; (void)out_size;
  const float* x = (const float*)d_in[0];   // (8,2048,512) f32
  const float* Wt = (const float*)d_in[1];  // (512,64) f32
  float* out = (float*)d_out;
  float* gatesT = (float*)d_ws;                                    // 4 MB
  double* Wd = (double*)((char*)d_ws + ((size_t)NROWS * NE * 4));  // 256 KB

  wprep_kernel<<<128, 256, 0, stream>>>(Wt, Wd);
  gate_kernel<<<GATE_BLOCKS, 256, 0, stream>>>(x, Wd, gatesT);
  topwrite_kernel<<<NG * NE, 256, 0, stream>>>(gatesT, out);
}

// Round 19
// 105.007 us; speedup vs baseline: 2.6711x; 1.0996x over previous
//
#include <hip/hip_runtime.h>
#include <math.h>
#include <stdint.h>

#define NG 8
#define GS 2048
#define DM 512
#define NE 64
#define CAP 32
#define NROWS (NG * GS)                       // 16384 total rows (g,s)
#define COMBINE_ELEMS (33554432ull)           // 8*2048*64*32

#define GATE_BLOCKS 512                       // 32 rows per block, 4 waves
#define XSTc 68                               // chunk row stride (words)
#define CHW (32 * XSTc)                       // chunk words (2176)
#define TBS 21                                // transpose buffer stride (odd)

typedef float f32x4 __attribute__((ext_vector_type(4)));
typedef double f64x2 __attribute__((ext_vector_type(2)));
typedef double f64x4 __attribute__((ext_vector_type(4)));
typedef unsigned long long u64;

// ---------------------------------------------------------------------------
// JAX Threefry-2x32 (partitionable path).  [verified: rounds 1,3-5,7-18]
// ---------------------------------------------------------------------------
__device__ __forceinline__ void threefry2x32(uint32_t k0, uint32_t k1,
                                             uint32_t x0, uint32_t x1,
                                             uint32_t& o0, uint32_t& o1) {
  uint32_t ks[3] = {k0, k1, k0 ^ k1 ^ 0x1BD11BDAu};
  x0 += ks[0];
  x1 += ks[1];
  const uint32_t rot[2][4] = {{13u, 15u, 26u, 6u}, {17u, 29u, 16u, 24u}};
#pragma unroll
  for (int i = 0; i < 5; ++i) {
#pragma unroll
    for (int j = 0; j < 4; ++j) {
      uint32_t r = rot[i & 1][j];
      x0 += x1;
      x1 = (x1 << r) | (x1 >> (32u - r));
      x1 ^= x0;
    }
    x0 += ks[(i + 1) % 3];
    x1 += ks[(i + 2) % 3] + (uint32_t)(i + 1);
  }
  o0 = x0;
  o1 = x1;
}

// XLA ErfInv (f32), Giles polynomial — constants bit-match xla math.cc.
__device__ __forceinline__ float erfinv_xla(float x) {
  float w = -log1pf(-x * x);
  float p;
  if (w < 5.0f) {
    w = w - 2.5f;
    p = 2.81022636e-08f;
    p = __fmaf_rn(p, w, 3.43273939e-07f);
    p = __fmaf_rn(p, w, -3.5233877e-06f);
    p = __fmaf_rn(p, w, -4.39150654e-06f);
    p = __fmaf_rn(p, w, 0.00021858087f);
    p = __fmaf_rn(p, w, -0.00125372503f);
    p = __fmaf_rn(p, w, -0.00417768164f);
    p = __fmaf_rn(p, w, 0.246640727f);
    p = __fmaf_rn(p, w, 1.50140941f);
  } else {
    w = sqrtf(w) - 3.0f;
    p = -0.000200214257f;
    p = __fmaf_rn(p, w, 0.000100950558f);
    p = __fmaf_rn(p, w, 0.00134934322f);
    p = __fmaf_rn(p, w, -0.00367342844f);
    p = __fmaf_rn(p, w, 0.00573950773f);
    p = __fmaf_rn(p, w, -0.0076224613f);
    p = __fmaf_rn(p, w, 0.00943887047f);
    p = __fmaf_rn(p, w, 1.00167406f);
    p = __fmaf_rn(p, w, 2.83297682f);
  }
  return p * x;
}

__device__ __forceinline__ float jax_normal(uint32_t idx) {
  uint32_t o0, o1;
  threefry2x32(0u, 42u, 0u, idx, o0, o1);
  uint32_t bits = o0 ^ o1;
  float f = __uint_as_float((bits >> 9) | 0x3f800000u) - 1.0f;  // [0,1)
  const float lo = __uint_as_float(0xBF7FFFFFu);                // -0.99999994
  float v = fmaxf(lo, f * 2.0f + lo);
  return __uint_as_float(0x3FB504F3u) * erfinv_xla(v);  // sqrt(2)_f32 * erfinv
}

// ---------------------------------------------------------------------------
// Kernel P: reformat W -> f64, layout Wd[row=kk*4+k4][i15][t].  [r14]
// ---------------------------------------------------------------------------
__global__ __launch_bounds__(256) void wprep_kernel(
    const float* __restrict__ Wt, double* __restrict__ Wd) {
  const int i = blockIdx.x * 256 + threadIdx.x;   // 0..32767
  const int t = i & 3, i15 = (i >> 2) & 15, row = i >> 6;
  Wd[i] = (double)Wt[row * NE + t * 16 + i15];
}

// ---------------------------------------------------------------------------
// Kernel 1: gate. ROUND-19 CHANGE: double-buffered chunk pipeline (T14
// issue-early/write-late). 8 chunks x 64 cols; per chunk each thread issues
// its 2 next-chunk global loads FIRST, computes 32 MFMAs (~2048 cyc, hides
// ~1000 cyc cold HBM latency — r17/r18 diagnosis: single-stage serialized a
// ~50 us cold fetch after every replay's cache-evicting output writes),
// then ds_writes + 1 barrier. Waves: wr splits rows, kh splits each chunk's
// kk (fp64 regroup ~1e-16, selection-safe). LDS 33.8 KB. Epilogue = R16.
// ---------------------------------------------------------------------------
__global__ __launch_bounds__(256) void gate_kernel(
    const float* __restrict__ x,    // (NROWS, 512)
    const double* __restrict__ Wd,  // (512, 16, 4) prepped
    float* __restrict__ gatesT) {   // (NG*NE, GS)
  __shared__ float xs[2 * CHW];     // 17408 B: two 32x68 chunk buffers
  __shared__ double pd[128 * 16];   // 16384 B: cross-wave partials
  const int gid = blockIdx.x;         // 0..511
  const int tid = threadIdx.x;
  const int l = tid & 63;             // lane
  const int w4 = tid >> 6;            // wave 0..3
  const int wr = w4 & 1;              // row-tile (rows 16wr..16wr+15)
  const int kh = w4 >> 1;             // kk-half within each chunk
  const int row0b = gid * 32;
  const int row0 = row0b + wr * 16;

  const int i15 = l & 15;
  const int k4 = l >> 4;

  // --- runtime probe: which x-row does acc[*][r] hold?  [verified r7-r18]
  f64x4 dr = {0., 0., 0., 0.};
  dr = __builtin_amdgcn_mfma_f64_16x16x4f64((double)i15, 0.25, dr, 0, 0, 0);
  int perm[4];
#pragma unroll
  for (int r = 0; r < 4; ++r) perm[r] = ((int)(dr[r] + 0.5)) & 15;

  // staging geometry: chunk = 32 rows x 16 f32x4; thread covers slots
  // {tid, tid+256}: r = slot>>4, c4 = (slot&15)*4 (words within chunk cols).
  const int sr0 = tid >> 4, sc0 = (tid & 15) << 2;
  const int sr1 = (tid + 256) >> 4, sc1 = ((tid + 256) & 15) << 2;
  const float* xg0 = x + (size_t)(row0b + sr0) * DM + sc0;
  const float* xg1 = x + (size_t)(row0b + sr1) * DM + sc1;
  float* xl0 = xs + sr0 * XSTc + sc0;   // + cur*CHW
  float* xl1 = xs + sr1 * XSTc + sc1;

  // prologue: stage chunk 0 into buffer 0
  {
    const f32x4 a0 = *(const f32x4*)xg0;
    const f32x4 a1 = *(const f32x4*)xg1;
    *(f32x4*)xl0 = a0;
    *(f32x4*)xl1 = a1;
  }
  __syncthreads();

  // main pipeline over 8 chunks of 16 kk-steps; wave does kkl in
  // [8kh, 8kh+8) of each chunk.
  f64x4 acc[4] = {{0., 0., 0., 0.}, {0., 0., 0., 0.},
                  {0., 0., 0., 0.}, {0., 0., 0., 0.}};
  const int abase = (wr * 16 + i15) * XSTc + k4;
  const int kl0 = kh * 8;
  for (int ck = 0; ck < 8; ++ck) {
    const int cur = ck & 1;
    // issue next-chunk loads FIRST (hidden under the MFMAs below)
    f32x4 a0, a1;
    const bool more = (ck < 7);
    if (more) {
      a0 = *(const f32x4*)(xg0 + (ck + 1) * 64);
      a1 = *(const f32x4*)(xg1 + (ck + 1) * 64);
    }
    // compute this chunk from bufs[cur]
    const float* ar = xs + cur * CHW + abase;
#pragma unroll
    for (int kkl = 0; kkl < 8; ++kkl) {
      const int kloc = kl0 + kkl;            // 0..15 within chunk
      const double a = (double)ar[kloc * 4];
      const int kk = ck * 16 + kloc;
      const double* wrow = Wd + ((size_t)((kk << 2) + k4)) * 64 + i15 * 4;
      const f64x2 b01 = *(const f64x2*)(wrow + 0);
      const f64x2 b23 = *(const f64x2*)(wrow + 2);
      acc[0] = __builtin_amdgcn_mfma_f64_16x16x4f64(a, b01[0], acc[0], 0, 0, 0);
      acc[1] = __builtin_amdgcn_mfma_f64_16x16x4f64(a, b01[1], acc[1], 0, 0, 0);
      acc[2] = __builtin_amdgcn_mfma_f64_16x16x4f64(a, b23[0], acc[2], 0, 0, 0);
      acc[3] = __builtin_amdgcn_mfma_f64_16x16x4f64(a, b23[1], acc[3], 0, 0, 0);
    }
    // write next chunk into the other buffer, then barrier
    if (more) {
      float* d0 = xs + (cur ^ 1) * CHW + sr0 * XSTc + sc0;
      float* d1 = xs + (cur ^ 1) * CHW + sr1 * XSTc + sc1;
      *(f32x4*)d0 = a0;
      *(f32x4*)d1 = a1;
    }
    __syncthreads();
  }

  // kh=1 waves dump partials; kh=0 waves add and finish.  [structure r16]
  if (kh == 1) {
    double* dst = pd + ((size_t)(wr * 64 + l)) * 16;
#pragma unroll
    for (int t = 0; t < 4; ++t)
#pragma unroll
      for (int r = 0; r < 4; ++r) dst[t * 4 + r] = acc[t][r];
  }
  __syncthreads();
  if (kh == 1) return;

  {
    const double* src = pd + ((size_t)(wr * 64 + l)) * 16;
#pragma unroll
    for (int t = 0; t < 4; ++t)
#pragma unroll
      for (int r = 0; r < 4; ++r) acc[t][r] += src[t * 4 + r];
  }

  // noise + fp64 softmax. acc[t][r] = logits[row0+perm[r]][e=16t+i15].
  float gatef[4][4];  // [t][r]
#pragma unroll
  for (int r = 0; r < 4; ++r) {
    const int row = row0 + perm[r];
    double v[4];
    double m = -1.0e300;
#pragma unroll
    for (int t = 0; t < 4; ++t) {
      const float logit = (float)acc[t][r];
      const float noised =
          logit + 0.015625f * jax_normal((uint32_t)(row * NE + 16 * t + i15));
      v[t] = (double)noised;
      m = fmax(m, v[t]);
    }
#pragma unroll
    for (int off = 1; off < 16; off <<= 1) m = fmax(m, __shfl_xor(m, off, 64));
    double s = 0.0;
#pragma unroll
    for (int t = 0; t < 4; ++t) {
      v[t] = exp(v[t] - m);
      s += v[t];
    }
#pragma unroll
    for (int off = 1; off < 16; off <<= 1) s += __shfl_xor(s, off, 64);
#pragma unroll
    for (int t = 0; t < 4; ++t) gatef[t][r] = (float)(v[t] / s);
  }

  // per-wave LDS transpose into dead staging buffers (kh=0 waves only;
  // wr regions disjoint: [0,1344) and [1344,2688) floats of xs).
  float* tb = xs + wr * (NE * TBS);
#pragma unroll
  for (int t = 0; t < 4; ++t)
#pragma unroll
    for (int r = 0; r < 4; ++r)
      tb[(16 * t + i15) * TBS + perm[r]] = gatef[t][r];

  const int g = row0 >> 11;
  const int s0 = row0 & (GS - 1);
  float* drow = gatesT + ((size_t)(g * NE + l)) * GS + s0;
#pragma unroll
  for (int c = 0; c < 4; ++c) {
    f32x4 o;
#pragma unroll
    for (int i = 0; i < 4; ++i) o[i] = tb[l * TBS + 4 * c + i];
    *(f32x4*)&drow[4 * c] = o;
  }
}

// ---------------------------------------------------------------------------
// Kernel 2: topwrite — fused bitonic top-32 + dense output write.  [r18]
// ---------------------------------------------------------------------------
__global__ __launch_bounds__(256) void topwrite_kernel(
    const float* __restrict__ gatesT,  // (NG*NE, GS)
    float* __restrict__ out) {         // combine ++ dispatch
  __shared__ u64 keys[CAP];
  __shared__ int sel_s[CAP];
  __shared__ float sel_v[CAP];
  __shared__ unsigned char c_of_s[GS];
  const int ge = blockIdx.x;  // == g*64 + e
  const int g = ge >> 6, e = ge & 63;
  const int tid = threadIdx.x;
  const int lane = tid & 63, w = tid >> 6;

  ((u64*)c_of_s)[tid] = ~0ull;

  if (w == 0) {
    const float* base = gatesT + (size_t)ge * GS;
    u64 K[32];
#pragma unroll
    for (int k = 0; k < 8; ++k) {
      const f32x4 t = *(const f32x4*)(base + k * 256 + lane * 4);
#pragma unroll
      for (int i = 0; i < 4; ++i) {
        const int s = k * 256 + lane * 4 + i;
        K[k * 4 + i] = ((u64)__float_as_uint(t[i]) << 32) | (u64)(2047 - s);
      }
    }
#pragma unroll
    for (int k = 2; k <= 32; k <<= 1) {
#pragma unroll
      for (int d = k >> 1; d > 0; d >>= 1) {
#pragma unroll
        for (int j = 0; j < 32; ++j) {
          const int ixj = j ^ d;
          if (ixj > j) {
            const bool asc = ((j & k) == 0);
            const u64 a = K[j], b = K[ixj];
            const bool sw = asc ? (a > b) : (a < b);
            K[j] = sw ? b : a;
            K[ixj] = sw ? a : b;
          }
        }
      }
    }
#pragma unroll
    for (int m = 1; m < 64; m <<= 1) {
      u64 tmp[32];
#pragma unroll
      for (int j = 0; j < 32; ++j) tmp[j] = __shfl_xor(K[31 - j], m, 64);
#pragma unroll
      for (int j = 0; j < 32; ++j) K[j] = (K[j] > tmp[j]) ? K[j] : tmp[j];
#pragma unroll
      for (int d = 16; d > 0; d >>= 1) {
#pragma unroll
        for (int j = 0; j < 32; ++j) {
          if ((j & d) == 0) {
            const u64 a = K[j], b = K[j | d];
            const bool sw = (a > b);
            K[j] = sw ? b : a;
            K[j | d] = sw ? a : b;
          }
        }
      }
    }
#pragma unroll
    for (int c = 0; c < CAP; ++c) {
      if (lane == c) keys[c] = K[31 - c];
    }
  }
  __syncthreads();

  if (tid < CAP) {
    const u64 key = keys[tid];
    sel_s[tid] = 2047 - (int)(key & 0x7FFull);
    sel_v[tid] = __uint_as_float((uint32_t)(key >> 32));
  }
  __syncthreads();
  if (tid < CAP) c_of_s[sel_s[tid]] = (unsigned char)tid;
  __syncthreads();

  // ---- dispatch (G,E,C,S): wave w writes rows c in [8w, 8w+8) ----
  float* drow_base = out + COMBINE_ELEMS + (size_t)ge * CAP * GS;
#pragma unroll
  for (int rr = 0; rr < 8; ++rr) {
    const int c = 8 * w + rr;
    const int sc = sel_s[c];
    float* rowp = drow_base + (size_t)c * GS;
#pragma unroll
    for (int j = 0; j < 8; ++j) {
      const int pos = j * 256 + lane * 4;
      f32x4 v;
      v[0] = (sc == pos + 0) ? 1.0f : 0.0f;
      v[1] = (sc == pos + 1) ? 1.0f : 0.0f;
      v[2] = (sc == pos + 2) ? 1.0f : 0.0f;
      v[3] = (sc == pos + 3) ? 1.0f : 0.0f;
      *(f32x4*)&rowp[pos] = v;
    }
  }

  // ---- combine (G,S,E,C): wave w writes rows s in [512w, 512w+512) ----
  const int pos = (lane & 7) * 4;
  for (int it = 0; it < 64; ++it) {
    const int s = 512 * w + 8 * it + (lane >> 3);
    const int c = c_of_s[s];
    const float val = (c != 255) ? sel_v[c & 31] : 0.0f;
    const int d = c - pos;
    f32x4 v;
    v[0] = (d == 0) ? val : 0.0f;
    v[1] = (d == 1) ? val : 0.0f;
    v[2] = (d == 2) ? val : 0.0f;
    v[3] = (d == 3) ? val : 0.0f;
    *(f32x4*)&out[(((size_t)(g * GS + s)) * NE + e) * CAP + pos] = v;
  }
}

extern "C" void kernel_launch(void* const* d_in, const int* in_sizes, int n_in,
                              void* d_out, int out_size, void* d_ws,
                              size_t ws_size, hipStream_t stream) {
  (void)in_sizes; (void)n_in; (void)ws_size; (void)out_size;
  const float* x = (const float*)d_in[0];   // (8,2048,512) f32
  const float* Wt = (const float*)d_in[1];  // (512,64) f32
  float* out = (float*)d_out;
  float* gatesT = (float*)d_ws;                                    // 4 MB
  double* Wd = (double*)((char*)d_ws + ((size_t)NROWS * NE * 4));  // 256 KB

  wprep_kernel<<<128, 256, 0, stream>>>(Wt, Wd);
  gate_kernel<<<GATE_BLOCKS, 256, 0, stream>>>(x, Wd, gatesT);
  topwrite_kernel<<<NG * NE, 256, 0, stream>>>(gatesT, out);
}